// Round 5
// baseline (281.055 us; speedup 1.0000x reference)
//
#include <hip/hip_runtime.h>
#include <math.h>

typedef __attribute__((ext_vector_type(8))) short bvec8;   // 8 bf16 (4 VGPRs)
typedef __attribute__((ext_vector_type(4))) short bvec4;
typedef __attribute__((ext_vector_type(4))) float fvec4;

#define MROWS 16384
#define TLEN  4096
#define DD    512
#define SWB   640
#define NT128 32
#define EPS_RMS 1.1920929e-07f

#define M_QKV    0
#define M_SCORE  1
#define M_RET    2
#define M_ORES   3
#define M_RSCALE 4
#define M_GELU   5
#define M_F32RES 6

__device__ __forceinline__ unsigned short f2bf(float f) {
  unsigned int u = __float_as_uint(f);
  u = (u + 0x7fffu + ((u >> 16) & 1u)) >> 16;   // RNE
  return (unsigned short)u;
}

__device__ __forceinline__ float wred_sum(float v) {
#pragma unroll
  for (int off = 32; off > 0; off >>= 1) v += __shfl_xor(v, off, 64);
  return v;
}
__device__ __forceinline__ float wred_max(float v) {
#pragma unroll
  for (int off = 32; off > 0; off >>= 1) v = fmaxf(v, __shfl_xor(v, off, 64));
  return v;
}

// bijective XCD-chunk swizzle for 1D grids with n%8==0; chunk = n/8
__device__ __forceinline__ int xcd_swz(int bid, int chunk) {
  return (bid & 7) * chunk + (bid >> 3);
}

// async 16B global->LDS (wave-uniform LDS base + lane*16; global src per-lane)
__device__ __forceinline__ void gload16(const unsigned short* g, unsigned short* l) {
  __builtin_amdgcn_global_load_lds((const __attribute__((address_space(1))) unsigned int*)g,
                                   (__attribute__((address_space(3))) unsigned int*)l,
                                   16, 0, 0);
}

// ---- 128x128xK MFMA core, 3-buffer 2-deep prefetch, RAW barriers + counted vmcnt ----
// As/Bs: 3 buffers x 4096 shorts, layout per buffer [kg(4)][row(128)][8]
__device__ __forceinline__ void gemm_core_db(
    const unsigned short* __restrict__ Ab, int lda,
    const unsigned short* __restrict__ Bb, int ldb,
    unsigned short* As, unsigned short* Bs,
    int K, int tid, int wm, int wn, fvec4 acc[4][4])
{
  int lane = tid & 63, w = tid >> 6;
  int r0 = tid & 127;
  int kg0 = tid >> 7;                    // 0 or 1
  const unsigned short* ApA = Ab + (size_t)r0 * lda + kg0 * 8;
  const unsigned short* ApB = ApA + 16;  // kg0+2
  const unsigned short* BpA = Bb + (size_t)r0 * ldb + kg0 * 8;
  const unsigned short* BpB = BpA + 16;
  unsigned short* lA0 = As + w * 512;
  unsigned short* lA1 = As + 2048 + w * 512;
  unsigned short* lB0 = Bs + w * 512;
  unsigned short* lB1 = Bs + 2048 + w * 512;
  int kgl = lane >> 4, l15 = lane & 15;
  int NK = K >> 5;

#define STAGE(kt, buf) do { \
    int _k0 = (kt) << 5; int _o = (buf) * 4096; \
    gload16(ApA + _k0, lA0 + _o); \
    gload16(ApB + _k0, lA1 + _o); \
    gload16(BpA + _k0, lB0 + _o); \
    gload16(BpB + _k0, lB1 + _o); \
  } while (0)

  STAGE(0, 0);
  if (NK > 1) STAGE(1, 1);
  int cur = 0;
  for (int t = 0; t < NK; ++t) {
    if (t + 2 < NK) {
      STAGE(t + 2, cur == 0 ? 2 : cur - 1);             // (cur+2)%3
      asm volatile("s_waitcnt vmcnt(8)" ::: "memory");  // tile t's 4 loads done; 8 stay in flight
    } else if (t + 1 < NK) {
      asm volatile("s_waitcnt vmcnt(4)" ::: "memory");
    } else {
      asm volatile("s_waitcnt vmcnt(0)" ::: "memory");
    }
    __builtin_amdgcn_s_barrier();        // raw: no vmcnt drain; all waves' tile-t loads visible
    const unsigned short* Ac = As + cur * 4096;
    const unsigned short* Bc = Bs + cur * 4096;
    bvec8 af[4], bf[4];
#pragma unroll
    for (int i = 0; i < 4; ++i) {
      af[i] = *(const bvec8*)&Ac[(kgl * 128 + wm + i * 16 + l15) * 8];
      bf[i] = *(const bvec8*)&Bc[(kgl * 128 + wn + i * 16 + l15) * 8];
    }
#pragma unroll
    for (int mi = 0; mi < 4; ++mi)
#pragma unroll
      for (int ni = 0; ni < 4; ++ni)
        acc[mi][ni] = __builtin_amdgcn_mfma_f32_16x16x32_bf16(af[mi], bf[ni], acc[mi][ni], 0, 0, 0);
    asm volatile("s_waitcnt lgkmcnt(0)" ::: "memory");  // ds_reads captured before rotation
    __builtin_amdgcn_s_barrier();
    cur = (cur == 2) ? 0 : cur + 1;
  }
#undef STAGE
}

// ---- convert the 7 fp32 param arrays ([512][128]) to bf16 ----
__global__ __launch_bounds__(256) void conv7_kernel(
    const float* __restrict__ basis, const float* __restrict__ qc, const float* __restrict__ kc,
    const float* __restrict__ vc, const float* __restrict__ oc, const float* __restrict__ rc,
    const float* __restrict__ wc,
    unsigned short* __restrict__ basisb, unsigned short* __restrict__ qcb,
    unsigned short* __restrict__ kcb, unsigned short* __restrict__ vcb,
    unsigned short* __restrict__ ocb, unsigned short* __restrict__ rcb,
    unsigned short* __restrict__ wcb)
{
  const float* src; unsigned short* dst;
  switch (blockIdx.y) {
    case 0: src = basis; dst = basisb; break;
    case 1: src = qc; dst = qcb; break;
    case 2: src = kc; dst = kcb; break;
    case 3: src = vc; dst = vcb; break;
    case 4: src = oc; dst = ocb; break;
    case 5: src = rc; dst = rcb; break;
    default: src = wc; dst = wcb; break;
  }
  int idx = blockIdx.x * 256 + threadIdx.x;
  float4 v = ((const float4*)src)[idx];
  union { bvec4 s; unsigned short u[4]; } o;
  o.u[0] = f2bf(v.x); o.u[1] = f2bf(v.y); o.u[2] = f2bf(v.z); o.u[3] = f2bf(v.w);
  ((bvec4*)dst)[idx] = o.s;
}

// ---- fused 6x weight-gen GEMM (512x512, K=128): z selects which ----
__global__ __launch_bounds__(256) void wgen_kernel(
    const unsigned short* __restrict__ basisb, const unsigned short* __restrict__ qcb,
    const unsigned short* __restrict__ kcb, const unsigned short* __restrict__ vcb,
    const unsigned short* __restrict__ ocb, const unsigned short* __restrict__ wcb,
    const unsigned short* __restrict__ rcb,
    unsigned short* __restrict__ qwT, unsigned short* __restrict__ kwT,
    unsigned short* __restrict__ vwT, unsigned short* __restrict__ owB,
    unsigned short* __restrict__ wrB, float* __restrict__ readLog)
{
  __shared__ __align__(16) unsigned short As[12288];
  __shared__ __align__(16) unsigned short Bs[12288];
  int tid = threadIdx.x, lane = tid & 63, wave = tid >> 6;
  int wm = (wave >> 1) * 64, wn = (wave & 1) * 64;
  int z = blockIdx.z;
  const unsigned short *Az, *Bz;
  switch (z) {
    case 0: Az = qcb;    Bz = basisb; break;
    case 1: Az = kcb;    Bz = basisb; break;
    case 2: Az = vcb;    Bz = basisb; break;
    case 3: Az = basisb; Bz = ocb;    break;
    case 4: Az = basisb; Bz = wcb;    break;
    default: Az = rcb;   Bz = basisb; break;
  }
  fvec4 acc[4][4] = {};
  gemm_core_db(Az + (size_t)blockIdx.y * 128 * 128, 128,
               Bz + (size_t)blockIdx.x * 128 * 128, 128,
               As, Bs, 128, tid, wm, wn, acc);
  int l15 = lane & 15, lr4 = (lane >> 4) << 2;
  int om = blockIdx.y * 128, on = blockIdx.x * 128;
  unsigned short* oz = (z == 0) ? qwT : (z == 1) ? kwT : (z == 2) ? vwT : (z == 3) ? owB : wrB;
#pragma unroll
  for (int mi = 0; mi < 4; ++mi)
#pragma unroll
    for (int ni = 0; ni < 4; ++ni)
#pragma unroll
      for (int j = 0; j < 4; ++j) {
        int r = om + wm + mi * 16 + lr4 + j;
        int c = on + wn + ni * 16 + l15;
        float v = acc[mi][ni][j];
        if (z == 5) readLog[(size_t)r * DD + c] = v;
        else        oz[(size_t)r * DD + c] = f2bf(v);
      }
}

// ---- xb[m][k] = bf16( x[m][k] * rsqrt(mean(x[m]^2)+eps) ); one wave per row ----
__global__ __launch_bounds__(256) void xbconv_kernel(const float* __restrict__ x,
                                                     unsigned short* __restrict__ xb)
{
  int row = blockIdx.x * 4 + (threadIdx.x >> 6);
  int lane = threadIdx.x & 63;
  const float4* p = (const float4*)(x + (size_t)row * DD);
  float4 a = p[lane * 2], b = p[lane * 2 + 1];
  float ss = a.x*a.x + a.y*a.y + a.z*a.z + a.w*a.w
           + b.x*b.x + b.y*b.y + b.z*b.z + b.w*b.w;
  ss = wred_sum(ss);
  float rs = rsqrtf(ss * (1.f / 512.f) + EPS_RMS);
  union { bvec8 s; unsigned short u[8]; } o;
  o.u[0]=f2bf(a.x*rs); o.u[1]=f2bf(a.y*rs); o.u[2]=f2bf(a.z*rs); o.u[3]=f2bf(a.w*rs);
  o.u[4]=f2bf(b.x*rs); o.u[5]=f2bf(b.y*rs); o.u[6]=f2bf(b.z*rs); o.u[7]=f2bf(b.w*rs);
  *(bvec8*)&xb[(size_t)row * DD + lane * 8] = o.s;
}

// ---- row softmax (512 elems) of fp32 logits -> bf16; one wave per row ----
__global__ __launch_bounds__(256) void softmax_row_kernel(const float* __restrict__ logit,
                                                          unsigned short* __restrict__ outb)
{
  int row = blockIdx.x * 4 + (threadIdx.x >> 6);
  int lane = threadIdx.x & 63;
  const float4* p = (const float4*)(logit + (size_t)row * DD);
  float4 a = p[lane * 2], b = p[lane * 2 + 1];
  float m = fmaxf(fmaxf(fmaxf(a.x, a.y), fmaxf(a.z, a.w)),
                  fmaxf(fmaxf(b.x, b.y), fmaxf(b.z, b.w)));
  m = wred_max(m);
  float e0=expf(a.x-m), e1=expf(a.y-m), e2=expf(a.z-m), e3=expf(a.w-m);
  float e4=expf(b.x-m), e5=expf(b.y-m), e6=expf(b.z-m), e7=expf(b.w-m);
  float s = wred_sum(e0+e1+e2+e3+e4+e5+e6+e7);
  float inv = 1.f / s;
  union { bvec8 sv; unsigned short u[8]; } o;
  o.u[0]=f2bf(e0*inv); o.u[1]=f2bf(e1*inv); o.u[2]=f2bf(e2*inv); o.u[3]=f2bf(e3*inv);
  o.u[4]=f2bf(e4*inv); o.u[5]=f2bf(e5*inv); o.u[6]=f2bf(e6*inv); o.u[7]=f2bf(e7*inv);
  *(bvec8*)&outb[(size_t)row * DD + lane * 8] = o.sv;
}

// ---- mixT[n][k] = bf16(mix[k][n]) ----
__global__ __launch_bounds__(256) void mixT_kernel(const float* __restrict__ mix,
                                                   unsigned short* __restrict__ mt)
{
  int idx = blockIdx.x * 256 + threadIdx.x;
  int n = idx & 511, k = idx >> 9;
  mt[(size_t)n * DD + k] = f2bf(mix[idx]);
}

// ---- finish rms scales: rs[i] = rsqrt(ssq[i]/512 + eps), in place ----
__global__ __launch_bounds__(256) void rsfin_kernel(float* __restrict__ ssq)
{
  int i = blockIdx.x * 256 + threadIdx.x;
  ssq[i] = rsqrtf(ssq[i] * (1.f / 512.f) + EPS_RMS);
}

// ================= main MFMA GEMM, 1D grid + per-mode decode + XCD swizzle =================
template<int MODE>
__global__ __launch_bounds__(256) void mfma1d(
    const unsigned short* __restrict__ A, int lda,
    const unsigned short* __restrict__ B, int ldb,
    const unsigned short* __restrict__ A2,
    void* outp, void* out2, void* out3, int ldo,
    const float* __restrict__ resid, const float* __restrict__ bias,
    const float* __restrict__ s0, const float* __restrict__ s1,
    const float* __restrict__ dlog, float* __restrict__ ssq,
    const float* __restrict__ rsv, int K)
{
  __shared__ __align__(16) unsigned short As[12288];
  __shared__ __align__(16) unsigned short Bs[12288];
  int tid = threadIdx.x, lane = tid & 63, wave = tid >> 6;
  int wm = (wave >> 1) * 64, wn = (wave & 1) * 64;

  const unsigned short *Ab, *Bb;
  size_t om, on;
  int bxx = 0, byy = 0, bzz = 0;
  int vmode = 0;
  int ldoR = ldo;

  if constexpr (MODE == M_QKV) {
    int nb = xcd_swz(blockIdx.x, 192);         // 1536 blocks
    if (nb < 1024) {                           // q|k proj: x-fastest over 8 N-tiles
      Ab = A + (size_t)(nb >> 3) * 128 * 512;
      Bb = B + (size_t)(nb & 7) * 128 * 512;
      om = (size_t)(nb >> 3) * 128; on = (size_t)(nb & 7) * 128;
      ldoR = 512;
    } else {                                   // vT = vwT @ xb^T
      vmode = 1;
      int m = nb - 1024;
      Ab = A2 + (size_t)(m >> 7) * 128 * 512;
      Bb = A + (size_t)(m & 127) * 128 * 512;
      om = (size_t)(m >> 7) * 128; on = (size_t)(m & 127) * 128;
      ldoR = MROWS;
    }
  } else if constexpr (MODE == M_SCORE) {
    int nb = xcd_swz(blockIdx.x, 80);          // 640 blocks
    bxx = nb % 5; int rr = nb / 5; byy = rr & 31; bzz = rr >> 5;
    Ab = A + (size_t)(bzz * TLEN + byy * 128) * lda;
    Bb = B + (size_t)(bzz * TLEN + (byy + bxx) * 128) * ldb;
    om = (size_t)(bzz * NT128 + byy) * 128; on = (size_t)bxx * 128;
  } else if constexpr (MODE == M_RET) {
    int nb = xcd_swz(blockIdx.x, 64);          // 512 blocks
    bxx = nb & 3; int rr = nb >> 2; byy = rr & 31; bzz = rr >> 5;
    Ab = A + (size_t)((bzz * NT128 + byy) * 128) * lda;
    Bb = B + (size_t)(bxx * 128) * ldb + (size_t)(bzz * TLEN + byy * 128);
    om = (size_t)(bzz * TLEN + byy * 128); on = (size_t)bxx * 128;
  } else {
    int nb = xcd_swz(blockIdx.x, 64);          // 512 blocks, x-fastest over 4 N-tiles
    bxx = nb & 3; byy = nb >> 2;
    Ab = A + (size_t)(byy * 128) * lda;
    Bb = B + (size_t)(bxx * 128) * ldb;
    om = (size_t)byy * 128; on = (size_t)bxx * 128;
  }

  fvec4 acc[4][4] = {};
  gemm_core_db(Ab, lda, Bb, ldb, As, Bs, K, tid, wm, wn, acc);

  int l15 = lane & 15, lr4 = (lane >> 4) << 2;
  float dlw = 0.f;
  if constexpr (MODE == M_SCORE) {
    float dl = *dlog;
    float dc = 1.f / (1.f + expf(-dl));
    dlw = log2f(dc);
  }
  float alpha = 1.f;
  if constexpr (MODE == M_ORES || MODE == M_F32RES) alpha = s0[0] * s1[0];

  float ss[4][4] = {};   // per-(mi,j) row sumsq partials (M_ORES)

#pragma unroll
  for (int mi = 0; mi < 4; ++mi) {
#pragma unroll
    for (int ni = 0; ni < 4; ++ni) {
#pragma unroll
      for (int j = 0; j < 4; ++j) {
        int rl = wm + mi * 16 + lr4 + j;
        int cl = wn + ni * 16 + l15;
        float v = acc[mi][ni][j];
        size_t r = om + rl, c = on + cl;
        if constexpr (MODE == M_QKV) {
          if (vmode == 0) {
            unsigned short* o = (c < 512) ? (unsigned short*)outp : (unsigned short*)out2;
            o[r * 512 + (c & 511)] = f2bf(v);
          } else {
            ((unsigned short*)out3)[r * (size_t)MROWS + c] = f2bf(v);
          }
        } else if constexpr (MODE == M_SCORE) {
          int d = bxx * 128 + (int)cl - rl;
          int sidx = (byy + bxx) * 128 + (int)cl;
          float w2 = (d >= 1 && sidx < TLEN) ? exp2f((float)(d - 1) * dlw) : 0.f;
          ((unsigned short*)outp)[r * (size_t)ldoR + c] = f2bf(v * w2);
        } else if constexpr (MODE == M_ORES) {
          size_t o = r * (size_t)ldoR + c;
          float t = resid[o] + alpha * v;
          ((float*)outp)[o] = t;                      // fp32 x1
          ((unsigned short*)out2)[o] = f2bf(t);       // bf16 x1 (unnormed)
          ss[mi][j] += t * t;
        } else if constexpr (MODE == M_F32RES) {
          size_t o = r * (size_t)ldoR + c;
          ((float*)outp)[o] = resid[o] + alpha * v;
        } else if constexpr (MODE == M_RSCALE) {
          ((unsigned short*)outp)[r * (size_t)ldoR + c] = f2bf(v * rsv[r]);
        } else if constexpr (MODE == M_GELU) {
          float t = v + bias[c];
          float g = 0.5f * t * (1.f + erff(t * 0.70710678118654752f));
          ((unsigned short*)outp)[r * (size_t)ldoR + c] = f2bf(g);
        } else { // M_RET
          ((unsigned short*)outp)[r * (size_t)ldoR + c] = f2bf(v);
        }
      }
    }
  }

  if constexpr (MODE == M_ORES) {
    // reduce ss over the 16 l15-lanes (quarter-wave), then one atomicAdd per row
#pragma unroll
    for (int mi = 0; mi < 4; ++mi)
#pragma unroll
      for (int j = 0; j < 4; ++j) {
        float s = ss[mi][j];
        s += __shfl_xor(s, 1, 64);
        s += __shfl_xor(s, 2, 64);
        s += __shfl_xor(s, 4, 64);
        s += __shfl_xor(s, 8, 64);
        if (l15 == 0) atomicAdd(&ssq[om + wm + mi * 16 + lr4 + j], s);
      }
  }
}

extern "C" void kernel_launch(void* const* d_in, const int* in_sizes, int n_in,
                              void* d_out, int out_size, void* d_ws, size_t ws_size,
                              hipStream_t stream) {
  const float* x       = (const float*)d_in[0];
  const float* basis   = (const float*)d_in[1];
  const float* qc      = (const float*)d_in[2];
  const float* kc      = (const float*)d_in[3];
  const float* vc      = (const float*)d_in[4];
  const float* oc      = (const float*)d_in[5];
  const float* decay_l = (const float*)d_in[6];
  const float* mos     = (const float*)d_in[7];
  const float* rc      = (const float*)d_in[8];
  const float* wc      = (const float*)d_in[9];
  const float* mix     = (const float*)d_in[10];
  const float* bias    = (const float*)d_in[11];
  const float* oos     = (const float*)d_in[12];
  const float* msc     = (const float*)d_in[13];
  const float* osc     = (const float*)d_in[14];
  float* out = (float*)d_out;

  char* w = (char*)d_ws;
  unsigned short* basisb = (unsigned short*)w; w += 65536 * 2;
  unsigned short* qcb    = (unsigned short*)w; w += 65536 * 2;
  unsigned short* kcb    = (unsigned short*)w; w += 65536 * 2;
  unsigned short* vcb    = (unsigned short*)w; w += 65536 * 2;
  unsigned short* ocb    = (unsigned short*)w; w += 65536 * 2;
  unsigned short* rcb    = (unsigned short*)w; w += 65536 * 2;
  unsigned short* wcb    = (unsigned short*)w; w += 65536 * 2;
  unsigned short* qwT = (unsigned short*)w; w += 262144 * 2;  // [c][v]   (kwT MUST follow)
  unsigned short* kwT = (unsigned short*)w; w += 262144 * 2;  // [c][v]
  unsigned short* vwT = (unsigned short*)w; w += 262144 * 2;  // [c][v]
  unsigned short* owB = (unsigned short*)w; w += 262144 * 2;  // [v][c]
  unsigned short* rdB = (unsigned short*)w; w += 262144 * 2;  // [c][v] softmaxed
  unsigned short* wrB = (unsigned short*)w; w += 262144 * 2;  // [v][c]
  unsigned short* mtB = (unsigned short*)w; w += 262144 * 2;  // [n][k]
  float* readLog = (float*)w; w += 262144 * 4;                // [c][v] fp32
  float* ssq = (float*)w; w += 16384 * 4;                     // row sumsq -> rs
  unsigned short* xb = (unsigned short*)w; w += (size_t)MROWS * DD * 2;
  unsigned short* qb = (unsigned short*)w; w += (size_t)MROWS * DD * 2;
  unsigned short* kb = (unsigned short*)w; w += (size_t)(MROWS + 640) * DD * 2;   // +band slack rows
  unsigned short* vT = (unsigned short*)w; w += ((size_t)DD * MROWS + 2048) * 2;  // [c][b*T+t] +slack
  unsigned short* sc = (unsigned short*)w; w += (size_t)MROWS * SWB * 2;          // band scores
  unsigned short* ret = (unsigned short*)w; w += (size_t)MROWS * DD * 2;

  // 0. zero rms-sumsq accumulator
  hipMemsetAsync(ssq, 0, 16384 * sizeof(float), stream);
  // 1. fp32 -> bf16 param conversions
  conv7_kernel<<<dim3(64, 7), 256, 0, stream>>>(basis, qc, kc, vc, oc, rc, wc,
                                                basisb, qcb, kcb, vcb, ocb, rcb, wcb);
  // 2. fused weight-gen (6 GEMMs 512x512 K=128)
  wgen_kernel<<<dim3(4, 4, 6), 256, 0, stream>>>(basisb, qcb, kcb, vcb, ocb, wcb, rcb,
                                                 qwT, kwT, vwT, owB, wrB, readLog);
  // 3. softmax over v (rows of readLog) -> bf16; mix transpose
  softmax_row_kernel<<<128, 256, 0, stream>>>(readLog, rdB);
  mixT_kernel<<<1024, 256, 0, stream>>>(mix, mtB);
  // 4. xb = bf16(rmsnorm(x))
  xbconv_kernel<<<4096, 256, 0, stream>>>(x, xb);
  // 5. fused q,k,vT projections (one 1536-block launch)
  mfma1d<M_QKV><<<1536, 256, 0, stream>>>(xb, DD, qwT, DD, vwT, qb, kb, vT, DD,
                                          nullptr, nullptr, nullptr, nullptr, nullptr, nullptr, nullptr, DD);
  // 6. banded decayed scores (128-row t-tiles, 640-wide band)
  mfma1d<M_SCORE><<<640, 256, 0, stream>>>(qb, DD, kb, DD, nullptr, sc, nullptr, nullptr, SWB,
                                           nullptr, nullptr, nullptr, nullptr, decay_l, nullptr, nullptr, DD);
  // 7. retrieved = band(scores) @ v
  mfma1d<M_RET><<<512, 256, 0, stream>>>(sc, SWB, vT, MROWS, nullptr, ret, nullptr, nullptr, DD,
                                         nullptr, nullptr, nullptr, nullptr, nullptr, nullptr, nullptr, SWB);
  // 8. x1 = x + msc*mos*(retrieved @ o_w.T); also bf16(x1)->xb and row-sumsq->ssq
  mfma1d<M_ORES><<<512, 256, 0, stream>>>(ret, DD, owB, DD, nullptr, out, xb, nullptr, DD,
                                          x, nullptr, msc, mos, nullptr, ssq, nullptr, DD);
  // 9. finish rms scales
  rsfin_kernel<<<64, 256, 0, stream>>>(ssq);
  // 10. tmp = rmsnorm(x1) @ read_w  (rms applied as row scale in epilogue)
  mfma1d<M_RSCALE><<<512, 256, 0, stream>>>(xb, DD, rdB, DD, nullptr, qb, nullptr, nullptr, DD,
                                            nullptr, nullptr, nullptr, nullptr, nullptr, nullptr, ssq, DD);
  // 11. vals = gelu(tmp @ mix + bias)
  mfma1d<M_GELU><<<512, 256, 0, stream>>>(qb, DD, mtB, DD, nullptr, kb, nullptr, nullptr, DD,
                                          nullptr, bias, nullptr, nullptr, nullptr, nullptr, nullptr, DD);
  // 12. out = x1 + op_scale*op_out_scale * (vals @ write_w.T), in-place residual
  mfma1d<M_F32RES><<<512, 256, 0, stream>>>(kb, DD, wrB, DD, nullptr, out, nullptr, nullptr, DD,
                                            out, nullptr, osc, oos, nullptr, nullptr, nullptr, DD);
}

// Round 6
// 201.233 us; speedup vs baseline: 1.3967x; 1.3967x over previous
//
#include <hip/hip_runtime.h>
#include <math.h>

typedef __attribute__((ext_vector_type(8))) short bvec8;   // 8 bf16 (4 VGPRs)
typedef __attribute__((ext_vector_type(4))) short bvec4;
typedef __attribute__((ext_vector_type(4))) float fvec4;
typedef unsigned short u16;

#define MROWS 16384
#define TLEN  4096
#define DD    512
#define SWB   640
#define NT128 32
#define EPS_RMS 1.1920929e-07f

#define M_QKV    0
#define M_SCORE  1
#define M_RET    2
#define M_ORES   3
#define M_RSCALE 4
#define M_GELU   5
#define M_F32RES 6

__device__ __forceinline__ u16 f2bf(float f) {
  unsigned int u = __float_as_uint(f);
  u = (u + 0x7fffu + ((u >> 16) & 1u)) >> 16;   // RNE
  return (u16)u;
}

__device__ __forceinline__ float wred_sum(float v) {
#pragma unroll
  for (int off = 32; off > 0; off >>= 1) v += __shfl_xor(v, off, 64);
  return v;
}
__device__ __forceinline__ float wred_max(float v) {
#pragma unroll
  for (int off = 32; off > 0; off >>= 1) v = fmaxf(v, __shfl_xor(v, off, 64));
  return v;
}

// bijective XCD-chunk swizzle for 1D grids with n%8==0; chunk = n/8
__device__ __forceinline__ int xcd_swz(int bid, int chunk) {
  return (bid & 7) * chunk + (bid >> 3);
}

#define GL16(g, l) __builtin_amdgcn_global_load_lds((const __attribute__((address_space(1))) unsigned int*)(g), (__attribute__((address_space(3))) unsigned int*)(l), 16, 0, 0)

// ==================== 128x128xK core, BK=64, 4-chunk phase-split schedule ====================
// LDS: 2 buffers x 4 chunks x 4096 shorts = 65536 B.
//   chunk 0: A rows [0,64)   x 64k, row-major 64 shorts/row, 16B-slot XOR (row&7)
//   chunk 1: A rows [64,128)
//   chunk 2: B rows [0,128) x k[0,32), 32 shorts/row, 16B-slot XOR (row&3)
//   chunk 3: B rows x k[32,64)
// Per tile j (4 phases mq x ks), stage tile j+1 chunks {A0,A1,B0,B1} one per phase.
// Waits: vmcnt(4) after phase1 (guarantees Bk1(j)); vmcnt(2)+lgkmcnt(0) after phase3
// (guarantees A0,A1,Bk0(j+1) and drains reads before buffer reuse). Tail: vmcnt(0) once.
__device__ __forceinline__ void gcore(
    const u16* __restrict__ Ab, int lda,
    const u16* __restrict__ Bb, int ldb,
    u16* lds, int NT, fvec4 (*acc)[4])
{
  const int tid = threadIdx.x, lane = tid & 63, w = tid >> 6;
  const int r = lane & 15, kg = lane >> 4;
  const int wn = (w & 1) * 64;
  const int ahalf = w >> 1;
  const int ar = tid >> 3, as = (tid & 7) ^ (ar & 7);      // A stage: row, pre-swizzled slot
  const int br = tid >> 2, bs = (tid & 3) ^ (br & 3);      // B stage
  const u16* a0r0 = Ab + (size_t)ar * lda + as * 8;
  const u16* a0r1 = a0r0 + (size_t)32 * lda;
  const u16* a1r0 = a0r0 + (size_t)64 * lda;
  const u16* a1r1 = a0r0 + (size_t)96 * lda;
  const u16* b0r0 = Bb + (size_t)br * ldb + bs * 8;
  const u16* b0r1 = b0r0 + (size_t)64 * ldb;
  u16* ldsw = lds + w * 512;                                // + lane*8 shorts implied by HW

  bvec8 af[2], bfr[4];
#define ST_A0(kt,p) { GL16(a0r0+(kt)*64, ldsw+(p)*16384+0);     GL16(a0r1+(kt)*64, ldsw+(p)*16384+2048); }
#define ST_A1(kt,p) { GL16(a1r0+(kt)*64, ldsw+(p)*16384+4096);  GL16(a1r1+(kt)*64, ldsw+(p)*16384+6144); }
#define ST_B0(kt,p) { GL16(b0r0+(kt)*64, ldsw+(p)*16384+8192);  GL16(b0r1+(kt)*64, ldsw+(p)*16384+10240); }
#define ST_B1(kt,p) { GL16(b0r0+(kt)*64+32, ldsw+(p)*16384+12288); GL16(b0r1+(kt)*64+32, ldsw+(p)*16384+14336); }
#define RD_A(mq,ks,p) { const u16* Ac = lds + (p)*16384 + ahalf*4096; \
  af[0] = *(const bvec8*)&Ac[((((mq)*2+0)*16+r)*64) + ((((ks)*4+kg)^(r&7)))*8]; \
  af[1] = *(const bvec8*)&Ac[((((mq)*2+1)*16+r)*64) + ((((ks)*4+kg)^(r&7)))*8]; }
#define RD_B(ks,p) { const u16* Bc = lds + (p)*16384 + 8192 + (ks)*4096; \
  _Pragma("unroll") for (int ni=0;ni<4;++ni) bfr[ni] = *(const bvec8*)&Bc[((wn+ni*16+r)*32) + ((kg^(r&3)))*8]; }
#define MM(mq) { _Pragma("unroll") for (int i=0;i<2;++i) _Pragma("unroll") for (int ni=0;ni<4;++ni) \
  acc[(mq)*2+i][ni] = __builtin_amdgcn_mfma_f32_16x16x32_bf16(af[i], bfr[ni], acc[(mq)*2+i][ni], 0,0,0); }

  // prologue: stage tile 0 into buffer 0; guarantee A0,A1,B0 (leave B1 in flight)
  ST_A0(0,0); ST_A1(0,0); ST_B0(0,0); ST_B1(0,0);
  asm volatile("s_waitcnt vmcnt(2)" ::: "memory");
  __builtin_amdgcn_s_barrier();
  asm volatile("" ::: "memory");
  int cur = 0;
  for (int j = 0; j < NT - 1; ++j) {
    int nx = cur ^ 1, kt = j + 1;
    // phase 0: (mq0, ks0)
    ST_A0(kt,nx); RD_A(0,0,cur); RD_B(0,cur); MM(0);
    // phase 1: (mq1, ks0)  -> guarantee Bk1(j) for phase 2
    ST_A1(kt,nx); RD_A(1,0,cur);
    asm volatile("s_waitcnt vmcnt(4)" ::: "memory");
    __builtin_amdgcn_s_barrier();
    asm volatile("" ::: "memory");
    MM(1);
    // phase 2: (mq0, ks1)
    ST_B0(kt,nx); RD_A(0,1,cur); RD_B(1,cur); MM(0);
    // phase 3: (mq1, ks1) -> drain reads, guarantee A0,A1,Bk0(j+1)
    ST_B1(kt,nx); RD_A(1,1,cur);
    asm volatile("s_waitcnt vmcnt(2) lgkmcnt(0)" ::: "memory");
    __builtin_amdgcn_s_barrier();
    asm volatile("" ::: "memory");
    MM(1);
    cur = nx;
  }
  // tail tile: no staging
  RD_A(0,0,cur); RD_B(0,cur); MM(0);
  RD_A(1,0,cur);
  asm volatile("s_waitcnt vmcnt(0)" ::: "memory");
  __builtin_amdgcn_s_barrier();
  asm volatile("" ::: "memory");
  MM(1);
  RD_A(0,1,cur); RD_B(1,cur); MM(0);
  RD_A(1,1,cur); MM(1);
#undef ST_A0
#undef ST_A1
#undef ST_B0
#undef ST_B1
#undef RD_A
#undef RD_B
#undef MM
}

// ---- convert the 7 fp32 param arrays ([512][128]) to bf16 ----
__global__ __launch_bounds__(256) void conv7_kernel(
    const float* __restrict__ basis, const float* __restrict__ qc, const float* __restrict__ kc,
    const float* __restrict__ vc, const float* __restrict__ oc, const float* __restrict__ rc,
    const float* __restrict__ wc,
    u16* __restrict__ basisb, u16* __restrict__ qcb, u16* __restrict__ kcb,
    u16* __restrict__ vcb, u16* __restrict__ ocb, u16* __restrict__ rcb,
    u16* __restrict__ wcb)
{
  const float* src; u16* dst;
  switch (blockIdx.y) {
    case 0: src = basis; dst = basisb; break;
    case 1: src = qc; dst = qcb; break;
    case 2: src = kc; dst = kcb; break;
    case 3: src = vc; dst = vcb; break;
    case 4: src = oc; dst = ocb; break;
    case 5: src = rc; dst = rcb; break;
    default: src = wc; dst = wcb; break;
  }
  int idx = blockIdx.x * 256 + threadIdx.x;
  float4 v = ((const float4*)src)[idx];
  union { bvec4 s; u16 u[4]; } o;
  o.u[0] = f2bf(v.x); o.u[1] = f2bf(v.y); o.u[2] = f2bf(v.z); o.u[3] = f2bf(v.w);
  ((bvec4*)dst)[idx] = o.s;
}

// ---- fused 6x weight-gen GEMM (512x512, K=128): z selects which ----
__global__ __launch_bounds__(256, 2) void wgen_kernel(
    const u16* __restrict__ basisb, const u16* __restrict__ qcb,
    const u16* __restrict__ kcb, const u16* __restrict__ vcb,
    const u16* __restrict__ ocb, const u16* __restrict__ wcb,
    const u16* __restrict__ rcb,
    u16* __restrict__ qwT, u16* __restrict__ kwT,
    u16* __restrict__ vwT, u16* __restrict__ owB,
    u16* __restrict__ wrB, float* __restrict__ readLog)
{
  __shared__ __align__(16) u16 lds[32768];
  int tid = threadIdx.x, lane = tid & 63, wave = tid >> 6;
  int wm = (wave >> 1) * 64, wn = (wave & 1) * 64;
  int z = blockIdx.z;
  const u16 *Az, *Bz;
  switch (z) {
    case 0: Az = qcb;    Bz = basisb; break;
    case 1: Az = kcb;    Bz = basisb; break;
    case 2: Az = vcb;    Bz = basisb; break;
    case 3: Az = basisb; Bz = ocb;    break;
    case 4: Az = basisb; Bz = wcb;    break;
    default: Az = rcb;   Bz = basisb; break;
  }
  fvec4 acc[4][4] = {};
  gcore(Az + (size_t)blockIdx.y * 128 * 128, 128,
        Bz + (size_t)blockIdx.x * 128 * 128, 128,
        lds, 2, acc);
  int l15 = lane & 15, lr4 = (lane >> 4) << 2;
  int om = blockIdx.y * 128, on = blockIdx.x * 128;
  u16* oz = (z == 0) ? qwT : (z == 1) ? kwT : (z == 2) ? vwT : (z == 3) ? owB : wrB;
#pragma unroll
  for (int mi = 0; mi < 4; ++mi)
#pragma unroll
    for (int ni = 0; ni < 4; ++ni)
#pragma unroll
      for (int j = 0; j < 4; ++j) {
        int rr = om + wm + mi * 16 + lr4 + j;
        int c = on + wn + ni * 16 + l15;
        float v = acc[mi][ni][j];
        if (z == 5) readLog[(size_t)rr * DD + c] = v;
        else        oz[(size_t)rr * DD + c] = f2bf(v);
      }
}

// ---- xb[m][k] = bf16( x[m][k] * rsqrt(mean(x[m]^2)+eps) ); one wave per row ----
__global__ __launch_bounds__(256) void xbconv_kernel(const float* __restrict__ x,
                                                     u16* __restrict__ xb)
{
  int row = blockIdx.x * 4 + (threadIdx.x >> 6);
  int lane = threadIdx.x & 63;
  const float4* p = (const float4*)(x + (size_t)row * DD);
  float4 a = p[lane * 2], b = p[lane * 2 + 1];
  float ss = a.x*a.x + a.y*a.y + a.z*a.z + a.w*a.w
           + b.x*b.x + b.y*b.y + b.z*b.z + b.w*b.w;
  ss = wred_sum(ss);
  float rs = rsqrtf(ss * (1.f / 512.f) + EPS_RMS);
  union { bvec8 s; u16 u[8]; } o;
  o.u[0]=f2bf(a.x*rs); o.u[1]=f2bf(a.y*rs); o.u[2]=f2bf(a.z*rs); o.u[3]=f2bf(a.w*rs);
  o.u[4]=f2bf(b.x*rs); o.u[5]=f2bf(b.y*rs); o.u[6]=f2bf(b.z*rs); o.u[7]=f2bf(b.w*rs);
  *(bvec8*)&xb[(size_t)row * DD + lane * 8] = o.s;
}

// ---- row softmax (512 elems) of fp32 logits -> bf16; one wave per row ----
__global__ __launch_bounds__(256) void softmax_row_kernel(const float* __restrict__ logit,
                                                          u16* __restrict__ outb)
{
  int row = blockIdx.x * 4 + (threadIdx.x >> 6);
  int lane = threadIdx.x & 63;
  const float4* p = (const float4*)(logit + (size_t)row * DD);
  float4 a = p[lane * 2], b = p[lane * 2 + 1];
  float m = fmaxf(fmaxf(fmaxf(a.x, a.y), fmaxf(a.z, a.w)),
                  fmaxf(fmaxf(b.x, b.y), fmaxf(b.z, b.w)));
  m = wred_max(m);
  float e0=expf(a.x-m), e1=expf(a.y-m), e2=expf(a.z-m), e3=expf(a.w-m);
  float e4=expf(b.x-m), e5=expf(b.y-m), e6=expf(b.z-m), e7=expf(b.w-m);
  float s = wred_sum(e0+e1+e2+e3+e4+e5+e6+e7);
  float inv = 1.f / s;
  union { bvec8 sv; u16 u[8]; } o;
  o.u[0]=f2bf(e0*inv); o.u[1]=f2bf(e1*inv); o.u[2]=f2bf(e2*inv); o.u[3]=f2bf(e3*inv);
  o.u[4]=f2bf(e4*inv); o.u[5]=f2bf(e5*inv); o.u[6]=f2bf(e6*inv); o.u[7]=f2bf(e7*inv);
  *(bvec8*)&outb[(size_t)row * DD + lane * 8] = o.sv;
}

// ---- mixT[n][k] = bf16(mix[k][n]) ----
__global__ __launch_bounds__(256) void mixT_kernel(const float* __restrict__ mix,
                                                   u16* __restrict__ mt)
{
  int idx = blockIdx.x * 256 + threadIdx.x;
  int n = idx & 511, k = idx >> 9;
  mt[(size_t)n * DD + k] = f2bf(mix[idx]);
}

// ---- finish rms scales: rs[i] = rsqrt(ssq[i]/512 + eps), in place ----
__global__ __launch_bounds__(256) void rsfin_kernel(float* __restrict__ ssq)
{
  int i = blockIdx.x * 256 + threadIdx.x;
  ssq[i] = rsqrtf(ssq[i] * (1.f / 512.f) + EPS_RMS);
}

// ================= main MFMA GEMM, 1D grid + per-mode decode + XCD swizzle =================
template<int MODE>
__global__ __launch_bounds__(256, 2) void mfma1d(
    const u16* __restrict__ A, int lda,
    const u16* __restrict__ B, int ldb,
    const u16* __restrict__ A2,
    void* outp, void* out2, void* out3, int ldo,
    const float* __restrict__ resid, const float* __restrict__ bias,
    const float* __restrict__ s0, const float* __restrict__ s1,
    const float* __restrict__ dlog, float* __restrict__ ssq,
    const float* __restrict__ rsv, int K)
{
  __shared__ __align__(16) u16 lds[32768];
  int tid = threadIdx.x, lane = tid & 63, wave = tid >> 6;
  int wm = (wave >> 1) * 64, wn = (wave & 1) * 64;

  const u16 *Ab, *Bb;
  size_t om, on;
  int bxx = 0, byy = 0, bzz = 0;
  int vmode = 0;
  int ldoR = ldo;

  if constexpr (MODE == M_QKV) {
    int nb = xcd_swz(blockIdx.x, 192);         // 1536 blocks
    if (nb < 1024) {                           // q|k proj: x-fastest over 8 N-tiles
      Ab = A + (size_t)(nb >> 3) * 128 * 512;
      Bb = B + (size_t)(nb & 7) * 128 * 512;
      om = (size_t)(nb >> 3) * 128; on = (size_t)(nb & 7) * 128;
      ldoR = 512;
    } else {                                   // vT = vwT @ xb^T
      vmode = 1;
      int m = nb - 1024;
      Ab = A2 + (size_t)(m >> 7) * 128 * 512;
      Bb = A + (size_t)(m & 127) * 128 * 512;
      om = (size_t)(m >> 7) * 128; on = (size_t)(m & 127) * 128;
      ldoR = MROWS;
    }
  } else if constexpr (MODE == M_SCORE) {
    int nb = xcd_swz(blockIdx.x, 80);          // 640 blocks
    bxx = nb % 5; int rr = nb / 5; byy = rr & 31; bzz = rr >> 5;
    Ab = A + (size_t)(bzz * TLEN + byy * 128) * lda;
    Bb = B + (size_t)(bzz * TLEN + (byy + bxx) * 128) * ldb;
    om = (size_t)(bzz * NT128 + byy) * 128; on = (size_t)bxx * 128;
  } else if constexpr (MODE == M_RET) {
    int nb = xcd_swz(blockIdx.x, 64);          // 512 blocks
    bxx = nb & 3; int rr = nb >> 2; byy = rr & 31; bzz = rr >> 5;
    Ab = A + (size_t)((bzz * NT128 + byy) * 128) * lda;
    Bb = B + (size_t)(bxx * 128) * ldb + (size_t)(bzz * TLEN + byy * 128);
    om = (size_t)(bzz * TLEN + byy * 128); on = (size_t)bxx * 128;
  } else {
    int nb = xcd_swz(blockIdx.x, 64);          // 512 blocks, x-fastest over 4 N-tiles
    bxx = nb & 3; byy = nb >> 2;
    Ab = A + (size_t)(byy * 128) * lda;
    Bb = B + (size_t)(bxx * 128) * ldb;
    om = (size_t)byy * 128; on = (size_t)bxx * 128;
  }

  fvec4 acc[4][4] = {};
  gcore(Ab, lda, Bb, ldb, lds, K >> 6, acc);

  int l15 = lane & 15, lr4 = (lane >> 4) << 2;
  float dlw = 0.f;
  if constexpr (MODE == M_SCORE) {
    float dl = *dlog;
    float dc = 1.f / (1.f + expf(-dl));
    dlw = log2f(dc);
  }
  float alpha = 1.f;
  if constexpr (MODE == M_ORES || MODE == M_F32RES) alpha = s0[0] * s1[0];

  float ss[4][4] = {};   // per-(mi,j) row sumsq partials (M_ORES)

#pragma unroll
  for (int mi = 0; mi < 4; ++mi) {
#pragma unroll
    for (int ni = 0; ni < 4; ++ni) {
#pragma unroll
      for (int j = 0; j < 4; ++j) {
        int rl = wm + mi * 16 + lr4 + j;
        int cl = wn + ni * 16 + l15;
        float v = acc[mi][ni][j];
        size_t r = om + rl, c = on + cl;
        if constexpr (MODE == M_QKV) {
          if (vmode == 0) {
            u16* o = (c < 512) ? (u16*)outp : (u16*)out2;
            o[r * 512 + (c & 511)] = f2bf(v);
          } else {
            ((u16*)out3)[r * (size_t)MROWS + c] = f2bf(v);
          }
        } else if constexpr (MODE == M_SCORE) {
          int d = bxx * 128 + (int)cl - rl;
          int sidx = (byy + bxx) * 128 + (int)cl;
          float w2 = (d >= 1 && sidx < TLEN) ? exp2f((float)(d - 1) * dlw) : 0.f;
          ((u16*)outp)[r * (size_t)ldoR + c] = f2bf(v * w2);
        } else if constexpr (MODE == M_ORES) {
          size_t o = r * (size_t)ldoR + c;
          float t = resid[o] + alpha * v;
          ((float*)outp)[o] = t;                      // fp32 x1
          ((u16*)out2)[o] = f2bf(t);                  // bf16 x1 (unnormed)
          ss[mi][j] += t * t;
        } else if constexpr (MODE == M_F32RES) {
          size_t o = r * (size_t)ldoR + c;
          ((float*)outp)[o] = resid[o] + alpha * v;
        } else if constexpr (MODE == M_RSCALE) {
          ((u16*)outp)[r * (size_t)ldoR + c] = f2bf(v * rsv[r]);
        } else if constexpr (MODE == M_GELU) {
          float t = v + bias[c];
          float g = 0.5f * t * (1.f + erff(t * 0.70710678118654752f));
          ((u16*)outp)[r * (size_t)ldoR + c] = f2bf(g);
        } else { // M_RET
          ((u16*)outp)[r * (size_t)ldoR + c] = f2bf(v);
        }
      }
    }
  }

  if constexpr (MODE == M_ORES) {
#pragma unroll
    for (int mi = 0; mi < 4; ++mi)
#pragma unroll
      for (int j = 0; j < 4; ++j) {
        float s = ss[mi][j];
        s += __shfl_xor(s, 1, 64);
        s += __shfl_xor(s, 2, 64);
        s += __shfl_xor(s, 4, 64);
        s += __shfl_xor(s, 8, 64);
        if (l15 == 0) atomicAdd(&ssq[om + wm + mi * 16 + lr4 + j], s);
      }
  }
}

extern "C" void kernel_launch(void* const* d_in, const int* in_sizes, int n_in,
                              void* d_out, int out_size, void* d_ws, size_t ws_size,
                              hipStream_t stream) {
  const float* x       = (const float*)d_in[0];
  const float* basis   = (const float*)d_in[1];
  const float* qc      = (const float*)d_in[2];
  const float* kc      = (const float*)d_in[3];
  const float* vc      = (const float*)d_in[4];
  const float* oc      = (const float*)d_in[5];
  const float* decay_l = (const float*)d_in[6];
  const float* mos     = (const float*)d_in[7];
  const float* rc      = (const float*)d_in[8];
  const float* wc      = (const float*)d_in[9];
  const float* mix     = (const float*)d_in[10];
  const float* bias    = (const float*)d_in[11];
  const float* oos     = (const float*)d_in[12];
  const float* msc     = (const float*)d_in[13];
  const float* osc     = (const float*)d_in[14];
  float* out = (float*)d_out;

  char* w = (char*)d_ws;
  u16* basisb = (u16*)w; w += 65536 * 2;
  u16* qcb    = (u16*)w; w += 65536 * 2;
  u16* kcb    = (u16*)w; w += 65536 * 2;
  u16* vcb    = (u16*)w; w += 65536 * 2;
  u16* ocb    = (u16*)w; w += 65536 * 2;
  u16* rcb    = (u16*)w; w += 65536 * 2;
  u16* wcb    = (u16*)w; w += 65536 * 2;
  u16* qwT = (u16*)w; w += 262144 * 2;  // [c][v]   (kwT MUST follow)
  u16* kwT = (u16*)w; w += 262144 * 2;  // [c][v]
  u16* vwT = (u16*)w; w += 262144 * 2;  // [c][v]
  u16* owB = (u16*)w; w += 262144 * 2;  // [v][c]
  u16* rdB = (u16*)w; w += 262144 * 2;  // [c][v] softmaxed
  u16* wrB = (u16*)w; w += 262144 * 2;  // [v][c]
  u16* mtB = (u16*)w; w += 262144 * 2;  // [n][k]
  float* readLog = (float*)w; w += 262144 * 4;                // [c][v] fp32
  float* ssq = (float*)w; w += 16384 * 4;                     // row sumsq -> rs
  u16* xb = (u16*)w; w += (size_t)MROWS * DD * 2;
  u16* qb = (u16*)w; w += (size_t)MROWS * DD * 2;
  u16* kb = (u16*)w; w += (size_t)(MROWS + 640) * DD * 2;     // +band slack rows
  u16* vT = (u16*)w; w += ((size_t)DD * MROWS + 2048) * 2;    // [c][b*T+t] +slack
  u16* sc = (u16*)w; w += (size_t)MROWS * SWB * 2;            // band scores
  u16* ret = (u16*)w; w += (size_t)MROWS * DD * 2;

  // 0. zero rms-sumsq accumulator
  hipMemsetAsync(ssq, 0, 16384 * sizeof(float), stream);
  // 1. fp32 -> bf16 param conversions
  conv7_kernel<<<dim3(64, 7), 256, 0, stream>>>(basis, qc, kc, vc, oc, rc, wc,
                                                basisb, qcb, kcb, vcb, ocb, rcb, wcb);
  // 2. fused weight-gen (6 GEMMs 512x512 K=128)
  wgen_kernel<<<dim3(4, 4, 6), 256, 0, stream>>>(basisb, qcb, kcb, vcb, ocb, wcb, rcb,
                                                 qwT, kwT, vwT, owB, wrB, readLog);
  // 3. softmax over v (rows of readLog) -> bf16; mix transpose
  softmax_row_kernel<<<128, 256, 0, stream>>>(readLog, rdB);
  mixT_kernel<<<1024, 256, 0, stream>>>(mix, mtB);
  // 4. xb = bf16(rmsnorm(x))
  xbconv_kernel<<<4096, 256, 0, stream>>>(x, xb);
  // 5. fused q,k,vT projections (one 1536-block launch)
  mfma1d<M_QKV><<<1536, 256, 0, stream>>>(xb, DD, qwT, DD, vwT, qb, kb, vT, DD,
                                          nullptr, nullptr, nullptr, nullptr, nullptr, nullptr, nullptr, DD);
  // 6. banded decayed scores (128-row t-tiles, 640-wide band)
  mfma1d<M_SCORE><<<640, 256, 0, stream>>>(qb, DD, kb, DD, nullptr, sc, nullptr, nullptr, SWB,
                                           nullptr, nullptr, nullptr, nullptr, decay_l, nullptr, nullptr, DD);
  // 7. retrieved = band(scores) @ v
  mfma1d<M_RET><<<512, 256, 0, stream>>>(sc, SWB, vT, MROWS, nullptr, ret, nullptr, nullptr, DD,
                                         nullptr, nullptr, nullptr, nullptr, nullptr, nullptr, nullptr, SWB);
  // 8. x1 = x + msc*mos*(retrieved @ o_w.T); also bf16(x1)->xb and row-sumsq->ssq
  mfma1d<M_ORES><<<512, 256, 0, stream>>>(ret, DD, owB, DD, nullptr, out, xb, nullptr, DD,
                                          x, nullptr, msc, mos, nullptr, ssq, nullptr, DD);
  // 9. finish rms scales
  rsfin_kernel<<<64, 256, 0, stream>>>(ssq);
  // 10. tmp = rmsnorm(x1) @ read_w  (rms applied as row scale in epilogue)
  mfma1d<M_RSCALE><<<512, 256, 0, stream>>>(xb, DD, rdB, DD, nullptr, qb, nullptr, nullptr, DD,
                                            nullptr, nullptr, nullptr, nullptr, nullptr, nullptr, ssq, DD);
  // 11. vals = gelu(tmp @ mix + bias)
  mfma1d<M_GELU><<<512, 256, 0, stream>>>(qb, DD, mtB, DD, nullptr, kb, nullptr, nullptr, DD,
                                          nullptr, bias, nullptr, nullptr, nullptr, nullptr, nullptr, DD);
  // 12. out = x1 + op_scale*op_out_scale * (vals @ write_w.T), in-place residual
  mfma1d<M_F32RES><<<512, 256, 0, stream>>>(kb, DD, wrB, DD, nullptr, out, nullptr, nullptr, DD,
                                            out, nullptr, osc, oos, nullptr, nullptr, nullptr, DD);
}